// Round 17
// baseline (310.184 us; speedup 1.0000x reference)
//
#include <hip/hip_runtime.h>

#define NG 64
#define HIDW 200
#define DIN 128
#define WKP 224          // weight k-dim (padded, zeros for k>=200)
#define POOL_NC 8

typedef _Float16 half4_t __attribute__((ext_vector_type(4)));
typedef _Float16 half8_t __attribute__((ext_vector_type(8)));
typedef float floatx4 __attribute__((ext_vector_type(4)));

// ---------------- fused prep: degree count + graph-start (y=0) / weight prep (y=1..4) --

__global__ void prep_kernel(const int* __restrict__ dst, int* __restrict__ counts,
                            const int* __restrict__ batch, int* __restrict__ gs,
                            int E, int n,
                            const float* __restrict__ W1, const float* __restrict__ W2,
                            const float* __restrict__ W3, const float* __restrict__ Wg,
                            _Float16* __restrict__ o1, _Float16* __restrict__ o2,
                            _Float16* __restrict__ o3, _Float16* __restrict__ og) {
  if (blockIdx.y == 0) {
    int i = blockIdx.x * 256 + threadIdx.x;
    if (i < E) atomicAdd(&counts[dst[i]], 1);
    if (i < n) {
      int b = batch[i];
      if (i == 0) {
        for (int g = 0; g <= b; ++g) gs[g] = 0;
      } else {
        int bp = batch[i - 1];
        for (int g = bp + 1; g <= b; ++g) gs[g] = i;
      }
      if (i == n - 1) {
        for (int g = b + 1; g <= NG; ++g) gs[g] = n;
      }
    }
  } else {
    int wsel = blockIdx.y - 1;
    const float* W = (wsel == 0) ? W1 : (wsel == 1) ? W2 : (wsel == 2) ? W3 : Wg;
    _Float16* WT = (wsel == 0) ? o1 : (wsel == 1) ? o2 : (wsel == 2) ? o3 : og;
    int K  = (wsel == 0) ? DIN : HIDW;
    int KP = (wsel == 0) ? DIN : WKP;
    int idx = blockIdx.x * 256 + threadIdx.x;
    if (idx >= 256 * KP) return;
    int col = idx / KP, k = idx % KP;
    float v = (col < HIDW && k < K) ? W[(long)k * HIDW + col] : 0.f;
    WT[idx] = (_Float16)v;
  }
}

// ---------------- scan phase 1: per-block sums + dinv ----------------

__global__ __launch_bounds__(256) void scan1_kernel(const int* __restrict__ counts,
                                                    int* __restrict__ blocksum,
                                                    float* __restrict__ dinv, int n) {
  __shared__ int s[256];
  int tid = threadIdx.x;
  int i = blockIdx.x * 256 + tid;
  int c = (i < n) ? counts[i] : 0;
  if (i < n) dinv[i] = rsqrtf((float)(c + 1));
  s[tid] = c;
  __syncthreads();
#pragma unroll
  for (int off = 128; off > 0; off >>= 1) {
    if (tid < off) s[tid] += s[tid + off];
    __syncthreads();
  }
  if (tid == 0) blocksum[blockIdx.x] = s[0];
}

// ---------------- scan phase 2+3 fused: row_ptr (block offset computed in-block) ------

__global__ __launch_bounds__(256) void scan3_kernel(const int* __restrict__ counts,
                                                    const int* __restrict__ blocksum,
                                                    int* __restrict__ row_ptr, int n, int nb) {
  __shared__ int bs[256];
  __shared__ int s[256];
  int tid = threadIdx.x;
  bs[tid] = (tid < blockIdx.x && tid < nb) ? blocksum[tid] : 0;
  __syncthreads();
#pragma unroll
  for (int off = 128; off > 0; off >>= 1) {
    if (tid < off) bs[tid] += bs[tid + off];
    __syncthreads();
  }
  int base = bs[0];

  int i = blockIdx.x * 256 + tid;
  int c = (i < n) ? counts[i] : 0;
  s[tid] = c;
  __syncthreads();
  for (int off = 1; off < 256; off <<= 1) {
    int t = (tid >= off) ? s[tid - off] : 0;
    __syncthreads();
    s[tid] += t;
    __syncthreads();
  }
  if (i < n) row_ptr[i] = base + s[tid] - c;
  if (i == n - 1) row_ptr[n] = base + s[tid];
}

__global__ void fill_kernel(const int* __restrict__ src, const int* __restrict__ dst,
                            const int* __restrict__ row_ptr, int* __restrict__ fill,
                            int* __restrict__ csr_src, int E) {
  int e = blockIdx.x * 256 + threadIdx.x;
  if (e >= E) return;
  int d = dst[e];
  int pos = row_ptr[d] + atomicAdd(&fill[d], 1);
  csr_src[pos] = src[e];
}

// ---------------- x f32 [n][128] -> dinv-scaled row-major f16 [n][128] ----------------

__global__ void cvt_kernel(const float* __restrict__ x, const float* __restrict__ dinv,
                           _Float16* __restrict__ g0, int n) {
  int t = blockIdx.x * 256 + threadIdx.x;
  if (t >= n * 32) return;
  int node = t >> 5, q = t & 31;
  float di = dinv[node];
  float4 v = *(const float4*)&x[(long)node * 128 + q * 4];
  half4_t r = {(_Float16)(di * v.x), (_Float16)(di * v.y),
               (_Float16)(di * v.z), (_Float16)(di * v.w)};
  ((half4_t*)g0)[(long)node * 32 + q] = r;
}

// ---------------- aggregation: z[i] = dinv[i] * (g[i] + sum_{s in N(i)} g[s]) ---------
// g pre-scaled by dinv, row-major, F half8-chunks/row (16 -> 128 feats, 25 -> 200).
// Wave per node; lane = (edge-parity esel, chunk fl): ONE VMEM instr gathers a full
// row for TWO edges (halved issue count at same bytes/MLP). Cross-group shfl_xor(32)
// once at the end. NT stores: don't evict the L2-resident gather table.

template <int F>
__global__ __launch_bounds__(256) void agg_kernel(const _Float16* __restrict__ g,
                                                  const int* __restrict__ row_ptr,
                                                  const int* __restrict__ csr_src,
                                                  const float* __restrict__ dinv,
                                                  _Float16* __restrict__ out, int n) {
  int node = blockIdx.x * 4 + (threadIdx.x >> 6);
  if (node >= n) return;
  int lane = threadIdx.x & 63;
  int esel = lane >> 5;          // edge parity within pair
  int fl = lane & 31;            // half8 chunk
  bool act = fl < F;
  int flc = act ? fl : 0;        // clamped chunk (inactive lanes read chunk 0: in-bounds)
  const half8_t* __restrict__ hp = (const half8_t*)g;
  int e0 = row_ptr[node], e1 = row_ptr[node + 1];
  float acc[8] = {0.f, 0.f, 0.f, 0.f, 0.f, 0.f, 0.f, 0.f};

  int e = e0;
  for (; e + 16 <= e1; e += 16) {          // 8 pairs = 16 edges, 8 VMEM instrs
    int sI[8];
#pragma unroll
    for (int j = 0; j < 8; ++j) sI[j] = csr_src[e + 2 * j + esel];
    half8_t vv[8];
#pragma unroll
    for (int j = 0; j < 8; ++j) vv[j] = hp[(long)sI[j] * F + flc];
#pragma unroll
    for (int j = 0; j < 8; ++j)
#pragma unroll
      for (int f = 0; f < 8; ++f) acc[f] += (float)vv[j][f];
  }
  if (e + 8 <= e1) {                        // 4 pairs
    int sI[4];
#pragma unroll
    for (int j = 0; j < 4; ++j) sI[j] = csr_src[e + 2 * j + esel];
    half8_t vv[4];
#pragma unroll
    for (int j = 0; j < 4; ++j) vv[j] = hp[(long)sI[j] * F + flc];
#pragma unroll
    for (int j = 0; j < 4; ++j)
#pragma unroll
      for (int f = 0; f < 8; ++f) acc[f] += (float)vv[j][f];
    e += 8;
  }
  for (; e + 2 <= e1; e += 2) {             // single pairs
    int s = csr_src[e + esel];
    half8_t v = hp[(long)s * F + flc];
#pragma unroll
    for (int f = 0; f < 8; ++f) acc[f] += (float)v[f];
  }
  if (e < e1 && esel == 0) {                // odd leftover edge: group 0 only
    int s = csr_src[e];
    half8_t v = hp[(long)s * F + flc];
#pragma unroll
    for (int f = 0; f < 8; ++f) acc[f] += (float)v[f];
  }

  // cross-group reduce (group0 + group1 edge subsets)
#pragma unroll
  for (int f = 0; f < 8; ++f) acc[f] += __shfl_xor(acc[f], 32);

  if (esel == 0 && act) {
    half8_t self = hp[(long)node * F + fl];
    float di = dinv[node];
    half8_t r;
#pragma unroll
    for (int f = 0; f < 8; ++f) r[f] = (_Float16)(di * (acc[f] + (float)self[f]));
    __builtin_nontemporal_store(r, (half8_t*)out + (long)node * F + fl);
  }
}

// ---------------- MFMA GEMM: LDS B-panel + XCD-family swizzle, 32-row waves -----------
// A: [N][AS] f16 (AS=200: k-overhang into next row x W-pad ZEROS = exact).
// W: [256][KP] f16 (k>=200 zero). out: [N][200] f16.
// Block = 4 waves x 32-row tiles (128 rows) x one 64-col strip; B staged once.
// Swizzle: strip=(b>>3)&3, rg=(b&7)+8*(b>>5); strips of a row-group share b%8 -> XCD.
// MODE 1 = relu, 2 = gated. DSCALE: out *= dinv[row].

template <int KP, int AS, int MODE, int DSCALE>
__global__ __launch_bounds__(256, 4) void mgemm_kernel(const _Float16* __restrict__ A,
                                                       const _Float16* __restrict__ WT,
                                                       const float* __restrict__ bias,
                                                       const float* __restrict__ dinv,
                                                       _Float16* __restrict__ out, int N) {
  constexpr int LDK = KP + 8;
  __shared__ _Float16 Bs[64][LDK];
  int tid = threadIdx.x;
  int b = blockIdx.x;
  int strip = (b >> 3) & 3;
  int rg = (b & 7) + 8 * (b >> 5);
  int col0 = strip * 64;

  {
    int c = tid >> 2;
    int ks = (tid & 3) * (KP / 4);
    const _Float16* gw = WT + (long)(col0 + c) * KP + ks;
#pragma unroll
    for (int j = 0; j < KP / 32; ++j)
      *(half8_t*)&Bs[c][ks + j * 8] = *(const half8_t*)(gw + j * 8);
  }
  __syncthreads();

  int lane = tid & 63;
  int wid = tid >> 6;
  int row0 = rg * 128 + wid * 32;
  if (row0 >= N) return;  // no barriers after this point
  int l15 = lane & 15;
  int lq = lane >> 4;

  const _Float16* __restrict__ pa = A + (long)(row0 + l15) * AS + lq * 8;

  floatx4 acc[2][4];
#pragma unroll
  for (int i = 0; i < 2; ++i)
#pragma unroll
    for (int j = 0; j < 4; ++j) acc[i][j] = (floatx4){0.f, 0.f, 0.f, 0.f};

#pragma unroll
  for (int k0 = 0; k0 < KP; k0 += 32) {
    half8_t a[2];
#pragma unroll
    for (int rf = 0; rf < 2; ++rf)
      a[rf] = *(const half8_t*)(pa + (long)rf * 16 * AS + k0);
#pragma unroll
    for (int cf = 0; cf < 4; ++cf) {
      half8_t bv = *(const half8_t*)&Bs[cf * 16 + l15][k0 + lq * 8];
#pragma unroll
      for (int rf = 0; rf < 2; ++rf)
        acc[rf][cf] = __builtin_amdgcn_mfma_f32_16x16x32_f16(a[rf], bv, acc[rf][cf], 0, 0, 0);
    }
  }

#pragma unroll
  for (int cf = 0; cf < 4; ++cf) {
    int col = col0 + cf * 16 + l15;
    if (col >= HIDW) continue;
    float bs = bias[col];
#pragma unroll
    for (int rf = 0; rf < 2; ++rf) {
      int rbase = row0 + rf * 16 + lq * 4;
#pragma unroll
      for (int j = 0; j < 4; ++j) {
        int row = rbase + j;
        float v = acc[rf][cf][j] + bs;
        if (MODE == 1) v = fmaxf(v, 0.f);
        if (MODE == 2) {
          float hv = (float)A[(long)row * AS + col];
          v = hv * (1.f / (1.f + __expf(-v)));
        }
        if (DSCALE) v *= dinv[row];
        out[(long)row * HIDW + col] = (_Float16)v;
      }
    }
  }
}

// ---------------- mean pool partials over gated row-major f16 [n][200] ----------------

__global__ __launch_bounds__(256) void pool_partial_kernel(const _Float16* __restrict__ gated,
                                                           const int* __restrict__ gs,
                                                           float* __restrict__ partial, int n) {
  int g = blockIdx.x;
  int c = blockIdx.y;
  int f = threadIdx.x;
  int s = gs[g], e = gs[g + 1];
  int len = e - s;
  int chunk = (len + POOL_NC - 1) / POOL_NC;
  int i0 = s + c * chunk;
  int i1 = i0 + chunk; if (i1 > e) i1 = e;
  if (f < HIDW) {
    float acc = 0.f;
    for (int i = i0; i < i1; ++i) acc += (float)gated[(long)i * HIDW + f];
    partial[(g * POOL_NC + c) * HIDW + f] = acc;
  }
}

// ---------------- classifier (fused pool-final): partial -> logits ----------------

__global__ void classifier_kernel(const float* __restrict__ partial,
                                  const int* __restrict__ gs,
                                  const float* __restrict__ Wc1, const float* __restrict__ bc1,
                                  const float* __restrict__ Wc2, const float* __restrict__ bc2,
                                  float* __restrict__ out) {
  int g = blockIdx.x;
  int tid = threadIdx.x;
  __shared__ float pg[HIDW];
  __shared__ float hid[100];
  if (tid < HIDW) {
    float acc = 0.f;
#pragma unroll
    for (int c = 0; c < POOL_NC; ++c) acc += partial[(g * POOL_NC + c) * HIDW + tid];
    float cnt = fmaxf((float)(gs[g + 1] - gs[g]), 1.f);
    pg[tid] = acc / cnt;
  }
  __syncthreads();
  if (tid < 100) {
    float a = bc1[tid];
    for (int k = 0; k < HIDW; ++k) a = fmaf(pg[k], Wc1[k * 100 + tid], a);
    hid[tid] = fmaxf(a, 0.f);
  }
  __syncthreads();
  if (tid < 2) {
    float a = bc2[tid];
    for (int k = 0; k < 100; ++k) a = fmaf(hid[k], Wc2[k * 2 + tid], a);
    out[g * 2 + tid] = a;
  }
}

// ---------------- launch ----------------

extern "C" void kernel_launch(void* const* d_in, const int* in_sizes, int n_in,
                              void* d_out, int out_size, void* d_ws, size_t ws_size,
                              hipStream_t stream) {
  const float* x    = (const float*)d_in[0];
  const int*   ei   = (const int*)d_in[1];
  const int*   batch= (const int*)d_in[2];
  const float* W1 = (const float*)d_in[3];  const float* b1 = (const float*)d_in[4];
  const float* W2 = (const float*)d_in[5];  const float* b2 = (const float*)d_in[6];
  const float* W3 = (const float*)d_in[7];  const float* b3 = (const float*)d_in[8];
  const float* Wg = (const float*)d_in[9];  const float* bg = (const float*)d_in[10];
  const float* Wc1= (const float*)d_in[11]; const float* bc1= (const float*)d_in[12];
  const float* Wc2= (const float*)d_in[13]; const float* bc2= (const float*)d_in[14];
  float* out = (float*)d_out;

  const int n = in_sizes[0] / DIN;     // 40000
  const int E = in_sizes[1] / 2;       // 640000
  const int* src = ei;
  const int* dst = ei + E;
  const int nb256 = (n + 255) / 256;   // 157 scan blocks

  // workspace carve-up (all segments 16B-aligned; buffers get +256 f16 tails for
  // the clamped-chunk gather overread)
  int* counts   = (int*)d_ws;               // n
  int* fill     = counts + n;               // n
  int* row_ptr  = fill + n;                 // n+4
  int* gs       = row_ptr + (n + 4);        // 68
  int* blocksum = gs + 68;                  // 1024
  float* dinv   = (float*)(blocksum + 1024);// n
  int* csr_src  = (int*)(dinv + n);         // E
  float* partial= (float*)(csr_src + E);    // 64*8*200
  _Float16* wt1 = (_Float16*)(partial + NG * POOL_NC * HIDW);  // 256*128
  _Float16* wt2 = wt1 + 256 * DIN;
  _Float16* wt3 = wt2 + 256 * WKP;
  _Float16* wtg = wt3 + 256 * WKP;
  _Float16* xh   = wtg + 256 * WKP;                   // [n][128] f16 (dinv-scaled)
  _Float16* bufA = xh + (long)n * DIN + 256;          // [n][200] f16 (+tail)
  _Float16* bufB = bufA + (long)n * HIDW + 256;       // [n][200] f16 (+tail)

  hipMemsetAsync(counts, 0, (size_t)2 * n * sizeof(int), stream);  // counts + fill

  int eb = (E + 255) / 256;
  // fused prep: build (y=0) + all 4 weight preps (y=1..4)
  dim3 pgrid0(eb, 5);
  prep_kernel<<<pgrid0, 256, 0, stream>>>(dst, counts, batch, gs, E, n,
                                          W1, W2, W3, Wg, wt1, wt2, wt3, wtg);
  scan1_kernel<<<nb256, 256, 0, stream>>>(counts, blocksum, dinv, n);
  // cvt needs dinv (from scan1): g0 = dinv * x
  cvt_kernel<<<(n * 32 + 255) / 256, 256, 0, stream>>>(x, dinv, xh, n);
  scan3_kernel<<<nb256, 256, 0, stream>>>(counts, blocksum, row_ptr, n, nb256);
  fill_kernel<<<eb, 256, 0, stream>>>(src, dst, row_ptr, fill, csr_src, E);

  int ab = (n + 3) / 4;                          // agg blocks (wave per node)
  int nrg = (n + 127) / 128;                     // 313 row-groups (128 rows each)
  int gb = ((nrg + 7) / 8) * 8 * 4;              // 1280: 8-aligned families x 4 strips

  // layer 1: z1 = agg(g0); bufB = dinv*relu(z1@W1+b1)
  agg_kernel<16><<<ab, 256, 0, stream>>>(xh, row_ptr, csr_src, dinv, bufA, n);
  mgemm_kernel<DIN, DIN, 1, 1><<<gb, 256, 0, stream>>>(bufA, wt1, b1, dinv, bufB, n);
  // layer 2
  agg_kernel<25><<<ab, 256, 0, stream>>>(bufB, row_ptr, csr_src, dinv, bufA, n);
  mgemm_kernel<WKP, HIDW, 1, 1><<<gb, 256, 0, stream>>>(bufA, wt2, b2, dinv, bufB, n);
  // layer 3 (h3 unscaled: feeds gate + pool, not another agg)
  agg_kernel<25><<<ab, 256, 0, stream>>>(bufB, row_ptr, csr_src, dinv, bufA, n);
  mgemm_kernel<WKP, HIDW, 1, 0><<<gb, 256, 0, stream>>>(bufA, wt3, b3, dinv, bufB, n);
  // gate + apply: bufA = h3 * sigmoid(h3 @ Wg + bg)
  mgemm_kernel<WKP, HIDW, 2, 0><<<gb, 256, 0, stream>>>(bufB, wtg, bg, dinv, bufA, n);
  // mean-pool partials + fused pool-final/classifier
  dim3 pgrid(NG, POOL_NC);
  pool_partial_kernel<<<pgrid, 256, 0, stream>>>(bufA, gs, partial, n);
  classifier_kernel<<<NG, 256, 0, stream>>>(partial, gs, Wc1, bc1, Wc2, bc2, out);
}

// Round 18
// 301.375 us; speedup vs baseline: 1.0292x; 1.0292x over previous
//
#include <hip/hip_runtime.h>

#define NG 64
#define HIDW 200
#define DIN 128
#define WKP 224          // weight k-dim (padded, zeros for k>=200)
#define POOL_NC 8

typedef _Float16 half4_t __attribute__((ext_vector_type(4)));
typedef _Float16 half8_t __attribute__((ext_vector_type(8)));
typedef float floatx4 __attribute__((ext_vector_type(4)));

// ---------------- build: degree count + graph-start table (fused) ----------------

__global__ void build_kernel(const int* __restrict__ dst, int* __restrict__ counts,
                             const int* __restrict__ batch, int* __restrict__ gs,
                             int E, int n) {
  int i = blockIdx.x * 256 + threadIdx.x;
  if (i < E) atomicAdd(&counts[dst[i]], 1);
  if (i < n) {
    int b = batch[i];
    if (i == 0) {
      for (int g = 0; g <= b; ++g) gs[g] = 0;
    } else {
      int bp = batch[i - 1];
      for (int g = bp + 1; g <= b; ++g) gs[g] = i;
    }
    if (i == n - 1) {
      for (int g = b + 1; g <= NG; ++g) gs[g] = n;
    }
  }
}

// ---------------- scan phase 1: per-block sums + dinv ----------------

__global__ __launch_bounds__(256) void scan1_kernel(const int* __restrict__ counts,
                                                    int* __restrict__ blocksum,
                                                    float* __restrict__ dinv, int n) {
  __shared__ int s[256];
  int tid = threadIdx.x;
  int i = blockIdx.x * 256 + tid;
  int c = (i < n) ? counts[i] : 0;
  if (i < n) dinv[i] = rsqrtf((float)(c + 1));
  s[tid] = c;
  __syncthreads();
#pragma unroll
  for (int off = 128; off > 0; off >>= 1) {
    if (tid < off) s[tid] += s[tid + off];
    __syncthreads();
  }
  if (tid == 0) blocksum[blockIdx.x] = s[0];
}

// ---------------- scan phase 2+3 fused: row_ptr (block offset computed in-block) ------

__global__ __launch_bounds__(256) void scan3_kernel(const int* __restrict__ counts,
                                                    const int* __restrict__ blocksum,
                                                    int* __restrict__ row_ptr, int n, int nb) {
  __shared__ int bs[256];
  __shared__ int s[256];
  int tid = threadIdx.x;
  // block offset = sum of blocksum[0..blockIdx.x)
  bs[tid] = (tid < blockIdx.x && tid < nb) ? blocksum[tid] : 0;
  __syncthreads();
#pragma unroll
  for (int off = 128; off > 0; off >>= 1) {
    if (tid < off) bs[tid] += bs[tid + off];
    __syncthreads();
  }
  int base = bs[0];

  int i = blockIdx.x * 256 + tid;
  int c = (i < n) ? counts[i] : 0;
  s[tid] = c;
  __syncthreads();
  for (int off = 1; off < 256; off <<= 1) {
    int t = (tid >= off) ? s[tid - off] : 0;
    __syncthreads();
    s[tid] += t;
    __syncthreads();
  }
  if (i < n) row_ptr[i] = base + s[tid] - c;
  if (i == n - 1) row_ptr[n] = base + s[tid];
}

__global__ void fill_kernel(const int* __restrict__ src, const int* __restrict__ dst,
                            const int* __restrict__ row_ptr, int* __restrict__ fill,
                            int* __restrict__ csr_src, int E) {
  int e = blockIdx.x * 256 + threadIdx.x;
  if (e >= E) return;
  int d = dst[e];
  int pos = row_ptr[d] + atomicAdd(&fill[d], 1);
  csr_src[pos] = src[e];
}

// ---------------- weight prep: W[k][200] fp32 -> WT [256][KP] f16, k>=200 zeroed ------

__global__ void wprep_kernel(const float* __restrict__ W1, const float* __restrict__ W2,
                             const float* __restrict__ W3, const float* __restrict__ Wg,
                             _Float16* __restrict__ o1, _Float16* __restrict__ o2,
                             _Float16* __restrict__ o3, _Float16* __restrict__ og) {
  int wsel = blockIdx.y;
  const float* W = (wsel == 0) ? W1 : (wsel == 1) ? W2 : (wsel == 2) ? W3 : Wg;
  _Float16* WT = (wsel == 0) ? o1 : (wsel == 1) ? o2 : (wsel == 2) ? o3 : og;
  int K  = (wsel == 0) ? DIN : HIDW;
  int KP = (wsel == 0) ? DIN : WKP;
  int idx = blockIdx.x * 256 + threadIdx.x;
  if (idx >= 256 * KP) return;
  int col = idx / KP, k = idx % KP;
  float v = (col < HIDW && k < K) ? W[(long)k * HIDW + col] : 0.f;
  WT[idx] = (_Float16)v;
}

// ---------------- x f32 [n][128] -> dinv-scaled row-major f16 [n][128] ----------------

__global__ void cvt_kernel(const float* __restrict__ x, const float* __restrict__ dinv,
                           _Float16* __restrict__ g0, int n) {
  int t = blockIdx.x * 256 + threadIdx.x;
  if (t >= n * 32) return;
  int node = t >> 5, q = t & 31;
  float di = dinv[node];
  float4 v = *(const float4*)&x[(long)node * 128 + q * 4];
  half4_t r = {(_Float16)(di * v.x), (_Float16)(di * v.y),
               (_Float16)(di * v.z), (_Float16)(di * v.w)};
  ((half4_t*)g0)[(long)node * 32 + q] = r;
}

// ---------------- aggregation: z[i] = dinv[i] * (g[i] + sum_{s in N(i)} g[s]) ---------
// g pre-scaled by dinv. Row-major [n][C*4] f16 (C=32: 128 feats; C=50: 200 feats,
// no pad bytes). Wave per node; unroll 16, tails 8/4/1. Plain stores (output is the
// next GEMM's input — keep it L2-resident; NT regressed, R17). Bytes-floor regime:
// per-XCD full-table stream at ~3.4 TB/s (5 kernel shapes converge here).

template <int C>
__global__ __launch_bounds__(256) void agg_kernel(const _Float16* __restrict__ g,
                                                  const int* __restrict__ row_ptr,
                                                  const int* __restrict__ csr_src,
                                                  const float* __restrict__ dinv,
                                                  _Float16* __restrict__ out, int n) {
  int node = blockIdx.x * 4 + (threadIdx.x >> 6);
  int lane = threadIdx.x & 63;
  if (node >= n || lane >= C) return;
  const half4_t* __restrict__ hp = (const half4_t*)g;
  int e0 = row_ptr[node], e1 = row_ptr[node + 1];
  half4_t self = hp[(long)node * C + lane];
  float ax = (float)self.x, ay = (float)self.y;
  float az = (float)self.z, aw = (float)self.w;

  int e = e0;
  for (; e + 16 <= e1; e += 16) {
    int sI[16];
#pragma unroll
    for (int j = 0; j < 16; ++j) sI[j] = csr_src[e + j];
    half4_t vv[16];
#pragma unroll
    for (int j = 0; j < 16; ++j) vv[j] = hp[(long)sI[j] * C + lane];
#pragma unroll
    for (int j = 0; j < 16; ++j) {
      ax += (float)vv[j].x; ay += (float)vv[j].y;
      az += (float)vv[j].z; aw += (float)vv[j].w;
    }
  }
  if (e + 8 <= e1) {
    int sI[8];
#pragma unroll
    for (int j = 0; j < 8; ++j) sI[j] = csr_src[e + j];
    half4_t vv[8];
#pragma unroll
    for (int j = 0; j < 8; ++j) vv[j] = hp[(long)sI[j] * C + lane];
#pragma unroll
    for (int j = 0; j < 8; ++j) {
      ax += (float)vv[j].x; ay += (float)vv[j].y;
      az += (float)vv[j].z; aw += (float)vv[j].w;
    }
    e += 8;
  }
  if (e + 4 <= e1) {
    int sI[4];
#pragma unroll
    for (int j = 0; j < 4; ++j) sI[j] = csr_src[e + j];
    half4_t vv[4];
#pragma unroll
    for (int j = 0; j < 4; ++j) vv[j] = hp[(long)sI[j] * C + lane];
#pragma unroll
    for (int j = 0; j < 4; ++j) {
      ax += (float)vv[j].x; ay += (float)vv[j].y;
      az += (float)vv[j].z; aw += (float)vv[j].w;
    }
    e += 4;
  }
  for (; e < e1; ++e) {
    int s = csr_src[e];
    half4_t v = hp[(long)s * C + lane];
    ax += (float)v.x; ay += (float)v.y; az += (float)v.z; aw += (float)v.w;
  }
  float di = dinv[node];
  half4_t r = {(_Float16)(di * ax), (_Float16)(di * ay),
               (_Float16)(di * az), (_Float16)(di * aw)};
  ((half4_t*)out)[(long)node * C + lane] = r;
}

// ---------------- MFMA GEMM: LDS B-panel + XCD-family swizzle, 32-row waves -----------
// A: [N][AS] f16 (AS=200: k-steps overhang into next row x W-pad ZEROS = exact).
// W: [256][KP] f16 (k>=200 zero). out: [N][200] f16.
// Block = 4 waves x 32-row tiles (128 rows) x one 64-col strip -> 1280 blocks.
// Swizzle: strip=(b>>3)&3, rg=(b&7)+8*(b>>5); strips of a row-group share b%8 -> XCD.
// MODE 1 = relu, 2 = gated. DSCALE: out *= dinv[row].

template <int KP, int AS, int MODE, int DSCALE>
__global__ __launch_bounds__(256, 4) void mgemm_kernel(const _Float16* __restrict__ A,
                                                       const _Float16* __restrict__ WT,
                                                       const float* __restrict__ bias,
                                                       const float* __restrict__ dinv,
                                                       _Float16* __restrict__ out, int N) {
  constexpr int LDK = KP + 8;
  __shared__ _Float16 Bs[64][LDK];
  int tid = threadIdx.x;
  int b = blockIdx.x;
  int strip = (b >> 3) & 3;
  int rg = (b & 7) + 8 * (b >> 5);
  int col0 = strip * 64;

  // stage B: 64 cols x KP, once
  {
    int c = tid >> 2;
    int ks = (tid & 3) * (KP / 4);
    const _Float16* gw = WT + (long)(col0 + c) * KP + ks;
#pragma unroll
    for (int j = 0; j < KP / 32; ++j)
      *(half8_t*)&Bs[c][ks + j * 8] = *(const half8_t*)(gw + j * 8);
  }
  __syncthreads();

  int lane = tid & 63;
  int wid = tid >> 6;
  int row0 = rg * 128 + wid * 32;
  if (row0 >= N) return;  // no barriers after this point
  int l15 = lane & 15;
  int lq = lane >> 4;

  const _Float16* __restrict__ pa = A + (long)(row0 + l15) * AS + lq * 8;

  floatx4 acc[2][4];
#pragma unroll
  for (int i = 0; i < 2; ++i)
#pragma unroll
    for (int j = 0; j < 4; ++j) acc[i][j] = (floatx4){0.f, 0.f, 0.f, 0.f};

#pragma unroll
  for (int k0 = 0; k0 < KP; k0 += 32) {
    half8_t a[2];
#pragma unroll
    for (int rf = 0; rf < 2; ++rf)
      a[rf] = *(const half8_t*)(pa + (long)rf * 16 * AS + k0);
#pragma unroll
    for (int cf = 0; cf < 4; ++cf) {
      half8_t bv = *(const half8_t*)&Bs[cf * 16 + l15][k0 + lq * 8];
#pragma unroll
      for (int rf = 0; rf < 2; ++rf)
        acc[rf][cf] = __builtin_amdgcn_mfma_f32_16x16x32_f16(a[rf], bv, acc[rf][cf], 0, 0, 0);
    }
  }

#pragma unroll
  for (int cf = 0; cf < 4; ++cf) {
    int col = col0 + cf * 16 + l15;
    if (col >= HIDW) continue;      // cols 200..255 not stored (no pads in layout)
    float bs = bias[col];
#pragma unroll
    for (int rf = 0; rf < 2; ++rf) {
      int rbase = row0 + rf * 16 + lq * 4;
#pragma unroll
      for (int j = 0; j < 4; ++j) {
        int row = rbase + j;
        float v = acc[rf][cf][j] + bs;
        if (MODE == 1) v = fmaxf(v, 0.f);
        if (MODE == 2) {
          float hv = (float)A[(long)row * AS + col];
          v = hv * (1.f / (1.f + __expf(-v)));
        }
        if (DSCALE) v *= dinv[row];
        out[(long)row * HIDW + col] = (_Float16)v;
      }
    }
  }
}

// ---------------- mean pool partials over gated row-major f16 [n][200] ----------------

__global__ __launch_bounds__(256) void pool_partial_kernel(const _Float16* __restrict__ gated,
                                                           const int* __restrict__ gs,
                                                           float* __restrict__ partial, int n) {
  int g = blockIdx.x;
  int c = blockIdx.y;
  int f = threadIdx.x;
  int s = gs[g], e = gs[g + 1];
  int len = e - s;
  int chunk = (len + POOL_NC - 1) / POOL_NC;
  int i0 = s + c * chunk;
  int i1 = i0 + chunk; if (i1 > e) i1 = e;
  if (f < HIDW) {
    float acc = 0.f;
    for (int i = i0; i < i1; ++i) acc += (float)gated[(long)i * HIDW + f];
    partial[(g * POOL_NC + c) * HIDW + f] = acc;
  }
}

// ---------------- classifier (fused pool-final): partial -> logits ----------------

__global__ void classifier_kernel(const float* __restrict__ partial,
                                  const int* __restrict__ gs,
                                  const float* __restrict__ Wc1, const float* __restrict__ bc1,
                                  const float* __restrict__ Wc2, const float* __restrict__ bc2,
                                  float* __restrict__ out) {
  int g = blockIdx.x;
  int tid = threadIdx.x;
  __shared__ float pg[HIDW];
  __shared__ float hid[100];
  if (tid < HIDW) {
    float acc = 0.f;
#pragma unroll
    for (int c = 0; c < POOL_NC; ++c) acc += partial[(g * POOL_NC + c) * HIDW + tid];
    float cnt = fmaxf((float)(gs[g + 1] - gs[g]), 1.f);
    pg[tid] = acc / cnt;
  }
  __syncthreads();
  if (tid < 100) {
    float a = bc1[tid];
    for (int k = 0; k < HIDW; ++k) a = fmaf(pg[k], Wc1[k * 100 + tid], a);
    hid[tid] = fmaxf(a, 0.f);
  }
  __syncthreads();
  if (tid < 2) {
    float a = bc2[tid];
    for (int k = 0; k < 100; ++k) a = fmaf(hid[k], Wc2[k * 2 + tid], a);
    out[g * 2 + tid] = a;
  }
}

// ---------------- launch ----------------

extern "C" void kernel_launch(void* const* d_in, const int* in_sizes, int n_in,
                              void* d_out, int out_size, void* d_ws, size_t ws_size,
                              hipStream_t stream) {
  const float* x    = (const float*)d_in[0];
  const int*   ei   = (const int*)d_in[1];
  const int*   batch= (const int*)d_in[2];
  const float* W1 = (const float*)d_in[3];  const float* b1 = (const float*)d_in[4];
  const float* W2 = (const float*)d_in[5];  const float* b2 = (const float*)d_in[6];
  const float* W3 = (const float*)d_in[7];  const float* b3 = (const float*)d_in[8];
  const float* Wg = (const float*)d_in[9];  const float* bg = (const float*)d_in[10];
  const float* Wc1= (const float*)d_in[11]; const float* bc1= (const float*)d_in[12];
  const float* Wc2= (const float*)d_in[13]; const float* bc2= (const float*)d_in[14];
  float* out = (float*)d_out;

  const int n = in_sizes[0] / DIN;     // 40000
  const int E = in_sizes[1] / 2;       // 640000
  const int* src = ei;
  const int* dst = ei + E;
  const int nb256 = (n + 255) / 256;   // 157 scan blocks

  // workspace carve-up (all segments 16B-aligned)
  int* counts   = (int*)d_ws;               // n
  int* fill     = counts + n;               // n
  int* row_ptr  = fill + n;                 // n+4
  int* gs       = row_ptr + (n + 4);        // 68
  int* blocksum = gs + 68;                  // 1024
  float* dinv   = (float*)(blocksum + 1024);// n
  int* csr_src  = (int*)(dinv + n);         // E
  float* partial= (float*)(csr_src + E);    // 64*8*200
  _Float16* wt1 = (_Float16*)(partial + NG * POOL_NC * HIDW);  // 256*128
  _Float16* wt2 = wt1 + 256 * DIN;
  _Float16* wt3 = wt2 + 256 * WKP;
  _Float16* wtg = wt3 + 256 * WKP;
  _Float16* xh   = wtg + 256 * WKP;             // [n][128] f16 (dinv-scaled)
  _Float16* bufA = xh + (long)n * DIN;          // [n][200] f16 (+64 tail)
  _Float16* bufB = bufA + (long)n * HIDW + 64;  // [n][200] f16 (+64 tail)

  hipMemsetAsync(counts, 0, (size_t)2 * n * sizeof(int), stream);  // counts + fill

  // weight prep: all 4 weights, one launch
  dim3 wgrid((256 * WKP + 255) / 256, 4);
  wprep_kernel<<<wgrid, 256, 0, stream>>>(W1, W2, W3, Wg, wt1, wt2, wt3, wtg);

  int eb = (E + 255) / 256;
  build_kernel<<<eb, 256, 0, stream>>>(dst, counts, batch, gs, E, n);
  scan1_kernel<<<nb256, 256, 0, stream>>>(counts, blocksum, dinv, n);
  // cvt needs dinv (from scan1): g0 = dinv * x
  cvt_kernel<<<(n * 32 + 255) / 256, 256, 0, stream>>>(x, dinv, xh, n);
  scan3_kernel<<<nb256, 256, 0, stream>>>(counts, blocksum, row_ptr, n, nb256);
  fill_kernel<<<eb, 256, 0, stream>>>(src, dst, row_ptr, fill, csr_src, E);

  int ab = (n + 3) / 4;                          // agg blocks (wave per node)
  int nrg = (n + 127) / 128;                     // 313 row-groups (128 rows each)
  int gb = ((nrg + 7) / 8) * 8 * 4;              // 1280: 8-aligned families x 4 strips

  // layer 1: z1 = agg(g0); bufB = dinv*relu(z1@W1+b1)
  agg_kernel<32><<<ab, 256, 0, stream>>>(xh, row_ptr, csr_src, dinv, bufA, n);
  mgemm_kernel<DIN, DIN, 1, 1><<<gb, 256, 0, stream>>>(bufA, wt1, b1, dinv, bufB, n);
  // layer 2
  agg_kernel<50><<<ab, 256, 0, stream>>>(bufB, row_ptr, csr_src, dinv, bufA, n);
  mgemm_kernel<WKP, HIDW, 1, 1><<<gb, 256, 0, stream>>>(bufA, wt2, b2, dinv, bufB, n);
  // layer 3 (h3 unscaled: feeds gate + pool, not another agg)
  agg_kernel<50><<<ab, 256, 0, stream>>>(bufB, row_ptr, csr_src, dinv, bufA, n);
  mgemm_kernel<WKP, HIDW, 1, 0><<<gb, 256, 0, stream>>>(bufA, wt3, b3, dinv, bufB, n);
  // gate + apply: bufA = h3 * sigmoid(h3 @ Wg + bg)
  mgemm_kernel<WKP, HIDW, 2, 0><<<gb, 256, 0, stream>>>(bufB, wtg, bg, dinv, bufA, n);
  // mean-pool partials + fused pool-final/classifier
  dim3 pgrid(NG, POOL_NC);
  pool_partial_kernel<<<pgrid, 256, 0, stream>>>(bufA, gs, partial, n);
  classifier_kernel<<<NG, 256, 0, stream>>>(partial, gs, Wc1, bc1, Wc2, bc2, out);
}